// Round 2
// baseline (315.387 us; speedup 1.0000x reference)
//
#include <hip/hip_runtime.h>
#include <cmath>
#include <complex>
#include <algorithm>

#define CAP_S 512   // max edges out of Co (out-degree ~Poisson(12), max << 512)
#define CAP_T 128   // max distinct targets of Co's edges (<= numS <= ~40)
#define CAP_M 4096  // max edges whose source is a target of Co (~12*35)

// ====================== host-side Wigner 3j (exact port, runs at .so load) =====================
namespace w3jhost {
static double fact(int n){
  static const double f[13]={1,1,2,6,24,120,720,5040,40320,362880,3628800,39916800,479001600};
  return f[n];
}
static double su2_cg(int j1,int m1,int j2,int m2,int j3,int m3){
  if(m3!=m1+m2) return 0.0;
  int vmin = std::max(std::max(-j1+j2+m3,-j1+m1),0);
  int vmax = std::min(std::min(j2+j3+m1, j3-j1+j2), j3+m3);
  double C = std::sqrt((double)(2*j3+1)*fact(j3+j1-j2)*fact(j3-j1+j2)*fact(j1+j2-j3)*fact(j3+m3)*fact(j3-m3)
            /(fact(j1+j2+j3+1)*fact(j1-m1)*fact(j1+m1)*fact(j2-m2)*fact(j2+m2)));
  double S=0.0;
  for(int v=vmin;v<=vmax;v++){
    double sgn = ((v+j2+m2)&1)?-1.0:1.0;
    S += sgn/fact(v)*fact(j2+j3+m1-v)*fact(j1-m1+v)/fact(j3-j1+j2-v)/fact(j3+m3-v)/fact(v+j1-j2-m3);
  }
  return C*S;
}
static void real_basis(int l, std::complex<double> q[7][7]){
  for(int i=0;i<7;i++)for(int j=0;j<7;j++) q[i][j]=0.0;
  const double r = std::sqrt(0.5);
  for(int m=-l;m<0;m++){ q[l+m][l-m]=r; q[l+m][l+m]=std::complex<double>(0.0,-r); }
  q[l][l]=1.0;
  for(int m=1;m<=l;m++){ double sg=(m&1)?-1.0:1.0; q[l+m][l+m]=sg*r; q[l+m][l-m]=std::complex<double>(0.0,sg*r); }
  std::complex<double> f;
  switch(l&3){ case 0: f={1,0};break; case 1: f={0,-1};break; case 2: f={-1,0};break; default: f={0,1};break; }
  for(int i=0;i<7;i++)for(int j=0;j<7;j++) q[i][j]*=f;
}
} // namespace w3jhost

struct W3JArg { float w[675]; };  // 7 paths concatenated, layout [i*(2l2+1)+j]*5+k

static W3JArg compute_w3j(){
  using namespace w3jhost;
  W3JArg out{};
  const int pl1[7]={0,1,1,2,2,3,3}, pl2[7]={2,1,3,0,2,1,3};
  int off=0;
  for(int p=0;p<7;p++){
    int l1=pl1[p], l2=pl2[p], l3=2;
    int n1=2*l1+1, n2=2*l2+1, n3=2*l3+1;
    double C[7][7][5];
    for(int i=0;i<7;i++)for(int k=0;k<7;k++)for(int n=0;n<5;n++) C[i][k][n]=0.0;
    for(int m1=-l1;m1<=l1;m1++)for(int m2=-l2;m2<=l2;m2++)
      if(std::abs(m1+m2)<=l3) C[l1+m1][l2+m2][l3+m1+m2]=su2_cg(l1,m1,l2,m2,l3,m1+m2);
    std::complex<double> Q1[7][7],Q2[7][7],Q3[7][7];
    real_basis(l1,Q1); real_basis(l2,Q2); real_basis(l3,Q3);
    double Cr[7][7][5]; double nrm=0.0;
    for(int a=0;a<n1;a++)for(int b=0;b<n2;b++)for(int c=0;c<n3;c++){
      std::complex<double> s(0.0,0.0);
      for(int i=0;i<n1;i++)for(int k=0;k<n2;k++)for(int n=0;n<n3;n++){
        double cv=C[i][k][n]; if(cv==0.0) continue;
        s += Q1[i][a]*Q2[k][b]*std::conj(Q3[n][c])*cv;  // einsum 'ij,kl,mn,ikn->jlm'
      }
      Cr[a][b][c]=s.real(); nrm+=s.real()*s.real();
    }
    nrm=std::sqrt(nrm);
    for(int a=0;a<n1;a++)for(int b=0;b<n2;b++)for(int c=0;c<n3;c++)
      out.w[off+(a*n2+b)*n3+c]=(float)(Cr[a][b][c]/nrm);
    off+=n1*n2*n3;
  }
  return out;
}
static const W3JArg g_w3j = compute_w3j();  // constant data; same every call

// ====================== device helpers ======================
__device__ __forceinline__ void calc_sh(float x,float y,float z,float* sh){
  float x2=x*x,y2=y*y,z2=z*z;
  const float s3=1.7320508075688772f, s5=2.2360679774997896f, s15=3.872983346207417f;
  const float s70_4=2.091650066335189f, s105=10.246950765959598f, s42_4=1.6201851746019651f;
  const float s7_2=1.3228756555322954f, s105_2=5.123475382979799f;
  sh[0]=1.f;
  sh[1]=s3*x; sh[2]=s3*y; sh[3]=s3*z;
  sh[4]=s15*x*z; sh[5]=s15*x*y; sh[6]=s5*(y2-0.5f*(x2+z2)); sh[7]=s15*y*z; sh[8]=0.5f*s15*(z2-x2);
  sh[9]=s70_4*x*(3.f*z2-x2); sh[10]=s105*x*y*z; sh[11]=s42_4*x*(5.f*y2-1.f);
  sh[12]=s7_2*y*(5.f*y2-3.f); sh[13]=s42_4*z*(5.f*y2-1.f); sh[14]=s105_2*y*(z2-x2); sh[15]=s70_4*z*(z2-3.f*x2);
}

// ====================== kernels ======================
// E-scan kernels are tiny-code (no expf, no big unrolled bodies); 4 edges/thread via int4.

__global__ void k_bincount(const int* __restrict__ eto, int E, int* __restrict__ counts){
  int i=blockIdx.x*blockDim.x+threadIdx.x;
  int e=i*4;
  if(e+3<E){
    int4 v=*reinterpret_cast<const int4*>(eto+e);
    atomicAdd(&counts[v.x],1); atomicAdd(&counts[v.y],1);
    atomicAdd(&counts[v.z],1); atomicAdd(&counts[v.w],1);
  } else {
    for(;e<E;e++) atomicAdd(&counts[eto[e]],1);
  }
}

__global__ void k_argmax(const int* __restrict__ counts, int N, unsigned long long* __restrict__ packed){
  __shared__ unsigned long long sm;
  if(threadIdx.x==0) sm=0ull;
  __syncthreads();
  int i=blockIdx.x*blockDim.x+threadIdx.x;
  unsigned long long v=0ull;
  if(i<N)
    v=(((unsigned long long)(unsigned)counts[i])<<32) | (unsigned long long)(0xFFFFFFFFu-(unsigned)i);
  atomicMax(&sm,v);
  __syncthreads();
  if(threadIdx.x==0) atomicMax(packed,sm);
}

// collect edges out of Co AND allocate dedup'd target slots in one pass (CAS claims)
__global__ void k_collect(const int* __restrict__ efrom, const int* __restrict__ eto, int E,
                          const unsigned long long* __restrict__ packed,
                          int* __restrict__ S, int* __restrict__ numS, int* __restrict__ numT,
                          int* __restrict__ flagslot){
  int i=blockIdx.x*blockDim.x+threadIdx.x;
  int e=i*4;
  int co=(int)(0xFFFFFFFFu-(unsigned)((*packed)&0xFFFFFFFFull));  // numpy argmax (first max)
  if(e+3<E){
    int4 v=*reinterpret_cast<const int4*>(efrom+e);
    int f[4]={v.x,v.y,v.z,v.w};
    #pragma unroll
    for(int q=0;q<4;q++){
      if(f[q]==co){
        int p=atomicAdd(numS,1);
        if(p<CAP_S) S[p]=e+q;
        int t=eto[e+q];
        int old=atomicCAS(&flagslot[t],0,-1);      // claim
        if(old==0){
          int s=atomicAdd(numT,1);
          flagslot[t]=(s<CAP_T)?(s+2):0;           // final slot (or drop if over cap)
        }
      }
    }
  } else {
    for(;e<E;e++){
      if(efrom[e]==co){
        int p=atomicAdd(numS,1);
        if(p<CAP_S) S[p]=e;
        int t=eto[e];
        int old=atomicCAS(&flagslot[t],0,-1);
        if(old==0){
          int s=atomicAdd(numT,1);
          flagslot[t]=(s<CAP_T)?(s+2):0;
        }
      }
    }
  }
}

// scan-only: push surviving edge ids into compact list M (tiny code, full occupancy)
__global__ void k_scanmid(const int* __restrict__ efrom, int E, const int* __restrict__ flagslot,
                          int* __restrict__ M, int* __restrict__ numM){
  int i=blockIdx.x*blockDim.x+threadIdx.x;
  int e=i*4;
  if(e+3<E){
    int4 v=*reinterpret_cast<const int4*>(efrom+e);
    int f0=flagslot[v.x], f1=flagslot[v.y], f2=flagslot[v.z], f3=flagslot[v.w];
    if(f0>=2){int p=atomicAdd(numM,1); if(p<CAP_M) M[p]=e;  }
    if(f1>=2){int p=atomicAdd(numM,1); if(p<CAP_M) M[p]=e+1;}
    if(f2>=2){int p=atomicAdd(numM,1); if(p<CAP_M) M[p]=e+2;}
    if(f3>=2){int p=atomicAdd(numM,1); if(p<CAP_M) M[p]=e+3;}
  } else {
    for(;e<E;e++)
      if(flagslot[efrom[e]]>=2){int p=atomicAdd(numM,1); if(p<CAP_M) M[p]=e;}
  }
}

// ====================== fused tail: mid accumulation (LDS) + second TP + output ======================
// Single block. All per-edge arrays FULLY UNROLLED -> registers (the round-1 k_midc
// was scratch-bound: VGPR=40 with 86 live floats => every MLP MAC was a local-memory RMW).
__global__ void __launch_bounds__(256,1)
k_tail(const float* __restrict__ x, const float* __restrict__ pos,
       const int* __restrict__ efrom, const int* __restrict__ eto,
       const float* __restrict__ W1, const float* __restrict__ W2,
       const float* __restrict__ tp2, const int* __restrict__ flagslot,
       const int* __restrict__ S, const int* __restrict__ numS,
       const int* __restrict__ M, const int* __restrict__ numM,
       W3JArg w3, float* __restrict__ out5){
  __shared__ float W1s[600];
  __shared__ float W2s[600];
  __shared__ float nmid[CAP_T*80];
  __shared__ float acc[5];
  const int tid=threadIdx.x;

  for(int i=tid;i<600;i+=256){ W1s[i]=W1[i]; W2s[i]=W2[i]; }
  for(int i=tid;i<CAP_T*80;i+=256) nmid[i]=0.f;
  if(tid<5) acc[tid]=0.f;
  __syncthreads();

  // ---- phase 1: per-edge radial MLP + sh -> LDS node_mid accumulation ----
  int nm=*numM; if(nm>CAP_M) nm=CAP_M;
  for(int t=tid;t<nm;t+=256){
    int e=M[t];
    int a=efrom[e];
    int fs=flagslot[a];
    if(fs<2) continue;
    int b=eto[e];
    float dx=pos[3*b]-pos[3*a], dy=pos[3*b+1]-pos[3*a+1], dz=pos[3*b+2]-pos[3*a+2];
    float d=sqrtf(dx*dx+dy*dy+dz*dz);
    float inv=1.f/d;
    float sh[16]; calc_sh(dx*inv,dy*inv,dz*inv,sh);

    float emb[20];
    const float step=3.5f/21.f;
    const float pref=(float)(1.14136*7.3890560989306495);  // 1.14136*e^2
    #pragma unroll
    for(int i=0;i<20;i++){
      float t2=(d-(float)(i+1)*step)/step;
      float A=t2+1.f, B=1.f-t2;
      float ua=(A>0.f)?expf(-1.f/A):0.f;
      float ub=(B>0.f)?expf(-1.f/B):0.f;
      emb[i]=pref*ua*ub;
    }
    float h[30];
    #pragma unroll
    for(int j=0;j<30;j++) h[j]=0.f;
    #pragma unroll
    for(int i=0;i<20;i++){
      float ei=emb[i];
      #pragma unroll
      for(int j=0;j<30;j++) h[j]+=ei*W1s[i*30+j];
    }
    #pragma unroll
    for(int j=0;j<30;j++){
      float z=h[j]*0.22360679774997896f;
      h[j]=1.679177f*z/(1.f+expf(-z));
    }
    float tw[20];
    #pragma unroll
    for(int c=0;c<20;c++) tw[c]=0.f;
    #pragma unroll
    for(int j=0;j<30;j++){
      float hj=h[j];
      #pragma unroll
      for(int c=0;c<20;c++) tw[c]+=hj*W2s[j*20+c];
    }
    // fold tw scale (1/sqrt30) and 1/sqrt(num_neighbors) into s
    float s=x[b]*0.18257418583505536f*0.4082482904638631f;
    int base=(fs-2)*80;
    const int offs[4]={0,5,20,45}, shoff[4]={0,1,4,9};
    #pragma unroll
    for(int l=0;l<4;l++){
      #pragma unroll
      for(int u=0;u<5;u++){
        float cfac=s*tw[l*5+u];
        #pragma unroll
        for(int mm=0;mm<2*l+1;mm++)
          atomicAdd(&nmid[base+offs[l]+u*(2*l+1)+mm], cfac*sh[shoff[l]+mm]);
      }
    }
  }
  __syncthreads();

  // ---- phase 2: second tensor product over edges out of Co ----
  int ns=*numS; if(ns>CAP_S) ns=CAP_S;
  for(int t=tid;t<ns;t+=256){
    int e=S[t];
    int a=efrom[e], b=eto[e];
    int fs=flagslot[b];
    if(fs<2) continue;
    int mbase=(fs-2)*80;
    float dx=pos[3*b]-pos[3*a], dy=pos[3*b+1]-pos[3*a+1], dz=pos[3*b+2]-pos[3*a+2];
    float d=sqrtf(dx*dx+dy*dy+dz*dz), inv=1.f/d;
    float sh[16]; calc_sh(dx*inv,dy*inv,dz*inv,sh);
    float o[5]={0.f,0.f,0.f,0.f,0.f};
    const int pl1[7]={0,1,1,2,2,3,3}, pl2[7]={2,1,3,0,2,1,3};
    const int wbase[7]={0,25,70,175,200,325,430};
    const int offs[4]={0,5,20,45}, shoff[4]={0,1,4,9};
    #pragma unroll
    for(int p=0;p<7;p++){
      const int l1=pl1[p], l2=pl2[p];
      const int n1=2*l1+1, n2=2*l2+1;
      #pragma unroll
      for(int u=0;u<5;u++){
        float tu=tp2[p*5+u];
        #pragma unroll
        for(int i=0;i<n1;i++){
          float mi=nmid[mbase+offs[l1]+u*n1+i]*tu;
          #pragma unroll
          for(int j=0;j<n2;j++){
            float c=mi*sh[shoff[l2]+j];
            #pragma unroll
            for(int k=0;k<5;k++) o[k]+=w3.w[wbase[p]+(i*n2+j)*5+k]*c;
          }
        }
      }
    }
    #pragma unroll
    for(int k=0;k<5;k++) atomicAdd(&acc[k],o[k]);
  }
  __syncthreads();
  const float scale=0.37796447300922725f*0.4082482904638631f;  // ALPHA2 * 1/sqrt(6)
  if(tid<5) out5[tid]=acc[tid]*scale;
}

// ====================== launch ======================
extern "C" void kernel_launch(void* const* d_in, const int* in_sizes, int n_in,
                              void* d_out, int out_size, void* d_ws, size_t ws_size,
                              hipStream_t stream){
  const float* x    =(const float*)d_in[0];
  const float* pos  =(const float*)d_in[1];
  const int*   efrom=(const int*)  d_in[2];
  const int*   eto  =(const int*)  d_in[3];
  const float* W1   =(const float*)d_in[4];
  const float* W2   =(const float*)d_in[5];
  const float* tp2  =(const float*)d_in[6];
  int N=in_sizes[0], E=in_sizes[2];

  char* ws=(char*)d_ws;
  size_t o=0;
  int* counts=(int*)(ws+o);                 o+=(size_t)N*4;
  int* flagslot=(int*)(ws+o);               o+=(size_t)N*4;
  o=(o+15)&~(size_t)15;
  unsigned long long* packed=(unsigned long long*)(ws+o); o+=8;
  int* numS=(int*)(ws+o);                   o+=4;
  int* numT=(int*)(ws+o);                   o+=4;
  int* numM=(int*)(ws+o);                   o+=4;
  size_t o_clear=o;                         // everything above must start zeroed
  o=(o+15)&~(size_t)15;
  int* S=(int*)(ws+o);                      o+=(size_t)CAP_S*4;
  int* M=(int*)(ws+o);                      o+=(size_t)CAP_M*4;

  hipMemsetAsync(d_ws,0,o_clear,stream);  // ws is re-poisoned 0xAA before every call

  const int tb=256;
  int nQ=(E+3)/4;                       // 4 edges per thread in the E-scans
  int gQ=(nQ+tb-1)/tb, gN=(N+tb-1)/tb;
  k_bincount<<<gQ,tb,0,stream>>>(eto,E,counts);
  k_argmax  <<<gN,tb,0,stream>>>(counts,N,packed);
  k_collect <<<gQ,tb,0,stream>>>(efrom,eto,E,packed,S,numS,numT,flagslot);
  k_scanmid <<<gQ,tb,0,stream>>>(efrom,E,flagslot,M,numM);
  k_tail    <<<1,tb,0,stream>>>(x,pos,efrom,eto,W1,W2,tp2,flagslot,S,numS,M,numM,g_w3j,(float*)d_out);
}

// Round 3
// 170.298 us; speedup vs baseline: 1.8520x; 1.8520x over previous
//
#include <hip/hip_runtime.h>
#include <cmath>
#include <complex>
#include <algorithm>

#define CAP_S 512   // max edges out of Co (out-degree ~Poisson(12))
#define CAP_T 64    // max distinct targets of Co's edges (<= out-degree of Co)
#define CAP_M 4096  // max edges whose source is a target of Co (~12*35)
#define EB    96    // per-batch edges staged in LDS in k_tail

// ====================== host-side Wigner 3j (exact port, runs at .so load) =====================
namespace w3jhost {
static double fact(int n){
  static const double f[13]={1,1,2,6,24,120,720,5040,40320,362880,3628800,39916800,479001600};
  return f[n];
}
static double su2_cg(int j1,int m1,int j2,int m2,int j3,int m3){
  if(m3!=m1+m2) return 0.0;
  int vmin = std::max(std::max(-j1+j2+m3,-j1+m1),0);
  int vmax = std::min(std::min(j2+j3+m1, j3-j1+j2), j3+m3);
  double C = std::sqrt((double)(2*j3+1)*fact(j3+j1-j2)*fact(j3-j1+j2)*fact(j1+j2-j3)*fact(j3+m3)*fact(j3-m3)
            /(fact(j1+j2+j3+1)*fact(j1-m1)*fact(j1+m1)*fact(j2-m2)*fact(j2+m2)));
  double S=0.0;
  for(int v=vmin;v<=vmax;v++){
    double sgn = ((v+j2+m2)&1)?-1.0:1.0;
    S += sgn/fact(v)*fact(j2+j3+m1-v)*fact(j1-m1+v)/fact(j3-j1+j2-v)/fact(j3+m3-v)/fact(v+j1-j2-m3);
  }
  return C*S;
}
static void real_basis(int l, std::complex<double> q[7][7]){
  for(int i=0;i<7;i++)for(int j=0;j<7;j++) q[i][j]=0.0;
  const double r = std::sqrt(0.5);
  for(int m=-l;m<0;m++){ q[l+m][l-m]=r; q[l+m][l+m]=std::complex<double>(0.0,-r); }
  q[l][l]=1.0;
  for(int m=1;m<=l;m++){ double sg=(m&1)?-1.0:1.0; q[l+m][l+m]=sg*r; q[l+m][l-m]=std::complex<double>(0.0,sg*r); }
  std::complex<double> f;
  switch(l&3){ case 0: f={1,0};break; case 1: f={0,-1};break; case 2: f={-1,0};break; default: f={0,1};break; }
  for(int i=0;i<7;i++)for(int j=0;j<7;j++) q[i][j]*=f;
}
} // namespace w3jhost

struct W3JArg { float w[675]; };  // 7 paths concatenated, layout [i*(2l2+1)+j]*5+k

static W3JArg compute_w3j(){
  using namespace w3jhost;
  W3JArg out{};
  const int pl1[7]={0,1,1,2,2,3,3}, pl2[7]={2,1,3,0,2,1,3};
  int off=0;
  for(int p=0;p<7;p++){
    int l1=pl1[p], l2=pl2[p], l3=2;
    int n1=2*l1+1, n2=2*l2+1, n3=2*l3+1;
    double C[7][7][5];
    for(int i=0;i<7;i++)for(int k=0;k<7;k++)for(int n=0;n<5;n++) C[i][k][n]=0.0;
    for(int m1=-l1;m1<=l1;m1++)for(int m2=-l2;m2<=l2;m2++)
      if(std::abs(m1+m2)<=l3) C[l1+m1][l2+m2][l3+m1+m2]=su2_cg(l1,m1,l2,m2,l3,m1+m2);
    std::complex<double> Q1[7][7],Q2[7][7],Q3[7][7];
    real_basis(l1,Q1); real_basis(l2,Q2); real_basis(l3,Q3);
    double Cr[7][7][5]; double nrm=0.0;
    for(int a=0;a<n1;a++)for(int b=0;b<n2;b++)for(int c=0;c<n3;c++){
      std::complex<double> s(0.0,0.0);
      for(int i=0;i<n1;i++)for(int k=0;k<n2;k++)for(int n=0;n<n3;n++){
        double cv=C[i][k][n]; if(cv==0.0) continue;
        s += Q1[i][a]*Q2[k][b]*std::conj(Q3[n][c])*cv;  // einsum 'ij,kl,mn,ikn->jlm'
      }
      Cr[a][b][c]=s.real(); nrm+=s.real()*s.real();
    }
    nrm=std::sqrt(nrm);
    for(int a=0;a<n1;a++)for(int b=0;b<n2;b++)for(int c=0;c<n3;c++)
      out.w[off+(a*n2+b)*n3+c]=(float)(Cr[a][b][c]/nrm);
    off+=n1*n2*n3;
  }
  return out;
}
static const W3JArg g_w3j = compute_w3j();  // constant data; same every call

// ====================== device helpers ======================
__device__ __forceinline__ void calc_sh(float x,float y,float z,float* sh){
  float x2=x*x,y2=y*y,z2=z*z;
  const float s3=1.7320508075688772f, s5=2.2360679774997896f, s15=3.872983346207417f;
  const float s70_4=2.091650066335189f, s105=10.246950765959598f, s42_4=1.6201851746019651f;
  const float s7_2=1.3228756555322954f, s105_2=5.123475382979799f;
  sh[0]=1.f;
  sh[1]=s3*x; sh[2]=s3*y; sh[3]=s3*z;
  sh[4]=s15*x*z; sh[5]=s15*x*y; sh[6]=s5*(y2-0.5f*(x2+z2)); sh[7]=s15*y*z; sh[8]=0.5f*s15*(z2-x2);
  sh[9]=s70_4*x*(3.f*z2-x2); sh[10]=s105*x*y*z; sh[11]=s42_4*x*(5.f*y2-1.f);
  sh[12]=s7_2*y*(5.f*y2-3.f); sh[13]=s42_4*z*(5.f*y2-1.f); sh[14]=s105_2*y*(z2-x2); sh[15]=s70_4*z*(z2-3.f*x2);
}

// ====================== kernels ======================
// E-scan kernels are tiny-code; 4 edges/thread via int4.

__global__ void k_bincount(const int* __restrict__ eto, int E, int* __restrict__ counts){
  int i=blockIdx.x*blockDim.x+threadIdx.x;
  int e=i*4;
  if(e+3<E){
    int4 v=*reinterpret_cast<const int4*>(eto+e);
    atomicAdd(&counts[v.x],1); atomicAdd(&counts[v.y],1);
    atomicAdd(&counts[v.z],1); atomicAdd(&counts[v.w],1);
  } else {
    for(;e<E;e++) atomicAdd(&counts[eto[e]],1);
  }
}

__global__ void k_argmax(const int* __restrict__ counts, int N, unsigned long long* __restrict__ packed){
  __shared__ unsigned long long sm;
  if(threadIdx.x==0) sm=0ull;
  __syncthreads();
  int i=blockIdx.x*blockDim.x+threadIdx.x;
  unsigned long long v=0ull;
  if(i<N)
    v=(((unsigned long long)(unsigned)counts[i])<<32) | (unsigned long long)(0xFFFFFFFFu-(unsigned)i);
  atomicMax(&sm,v);
  __syncthreads();
  if(threadIdx.x==0) atomicMax(packed,sm);
}

// collect edges out of Co AND allocate dedup'd target slots in one pass (CAS claims)
__global__ void k_collect(const int* __restrict__ efrom, const int* __restrict__ eto, int E,
                          const unsigned long long* __restrict__ packed,
                          int* __restrict__ S, int* __restrict__ numS, int* __restrict__ numT,
                          int* __restrict__ flagslot){
  int i=blockIdx.x*blockDim.x+threadIdx.x;
  int e=i*4;
  int co=(int)(0xFFFFFFFFu-(unsigned)((*packed)&0xFFFFFFFFull));  // numpy argmax (first max)
  if(e+3<E){
    int4 v=*reinterpret_cast<const int4*>(efrom+e);
    int f[4]={v.x,v.y,v.z,v.w};
    #pragma unroll
    for(int q=0;q<4;q++){
      if(f[q]==co){
        int p=atomicAdd(numS,1);
        if(p<CAP_S) S[p]=e+q;
        int t=eto[e+q];
        int old=atomicCAS(&flagslot[t],0,-1);      // claim
        if(old==0){
          int s=atomicAdd(numT,1);
          flagslot[t]=(s<CAP_T)?(s+2):0;           // final slot (or drop if over cap)
        }
      }
    }
  } else {
    for(;e<E;e++){
      if(efrom[e]==co){
        int p=atomicAdd(numS,1);
        if(p<CAP_S) S[p]=e;
        int t=eto[e];
        int old=atomicCAS(&flagslot[t],0,-1);
        if(old==0){
          int s=atomicAdd(numT,1);
          flagslot[t]=(s<CAP_T)?(s+2):0;
        }
      }
    }
  }
}

// scan-only: push surviving edge ids into compact list M
__global__ void k_scanmid(const int* __restrict__ efrom, int E, const int* __restrict__ flagslot,
                          int* __restrict__ M, int* __restrict__ numM){
  int i=blockIdx.x*blockDim.x+threadIdx.x;
  int e=i*4;
  if(e+3<E){
    int4 v=*reinterpret_cast<const int4*>(efrom+e);
    int f0=flagslot[v.x], f1=flagslot[v.y], f2=flagslot[v.z], f3=flagslot[v.w];
    if(f0>=2){int p=atomicAdd(numM,1); if(p<CAP_M) M[p]=e;  }
    if(f1>=2){int p=atomicAdd(numM,1); if(p<CAP_M) M[p]=e+1;}
    if(f2>=2){int p=atomicAdd(numM,1); if(p<CAP_M) M[p]=e+2;}
    if(f3>=2){int p=atomicAdd(numM,1); if(p<CAP_M) M[p]=e+3;}
  } else {
    for(;e<E;e++)
      if(flagslot[efrom[e]]>=2){int p=atomicAdd(numM,1); if(p<CAP_M) M[p]=e;}
  }
}

// ====================== fused tail: phased task-parallel pipeline ======================
// One block of 1024 threads (16 waves, 4/SIMD). The round-2 version gave each thread
// one edge's ENTIRE serial chain (~2000 dependent LDS ops) with 1 wave/SIMD -> 205us
// latency-bound. Here each phase splits edges across fine-grained tasks (20-30
// independent LDS MACs per task), staged through LDS, so waves hide each other's latency.
__global__ void __launch_bounds__(1024,1)
k_tail(const float* __restrict__ x, const float* __restrict__ pos,
       const int* __restrict__ efrom, const int* __restrict__ eto,
       const float* __restrict__ W1, const float* __restrict__ W2,
       const float* __restrict__ tp2, const int* __restrict__ flagslot,
       const int* __restrict__ S, const int* __restrict__ numS,
       const int* __restrict__ M, const int* __restrict__ numM,
       W3JArg w3, float* __restrict__ out5){
  __shared__ float W1s[600];
  __shared__ float W2s[600];
  __shared__ float w3s[675];
  __shared__ float tp2s[35];
  __shared__ float nmid[CAP_T*80];
  __shared__ float shs[EB*16];
  __shared__ float embs[EB*20];
  __shared__ float hs[EB*30];
  __shared__ float tws[EB*20];
  __shared__ float es_[EB];
  __shared__ float dd_[EB];
  __shared__ int   sl_[EB];
  __shared__ float acc[5];
  const int tid=threadIdx.x;

  for(int i=tid;i<600;i+=1024){ W1s[i]=W1[i]; W2s[i]=W2[i]; }
  for(int i=tid;i<675;i+=1024) w3s[i]=w3.w[i];
  if(tid<35) tp2s[tid]=tp2[tid];
  for(int i=tid;i<CAP_T*80;i+=1024) nmid[i]=0.f;
  if(tid<5) acc[tid]=0.f;
  __syncthreads();

  // ---------------- phase 1: node_mid accumulation over M-edges ----------------
  int nm=*numM; if(nm>CAP_M) nm=CAP_M;
  for(int base=0;base<nm;base+=EB){
    int cnt=min(EB,nm-base);
    // A0: per-edge meta + spherical harmonics
    if(tid<cnt){
      int e=M[base+tid];
      int a=efrom[e];
      int fs=flagslot[a];
      if(fs<2){ sl_[tid]=-1; }
      else{
        int b=eto[e];
        float dx=pos[3*b]-pos[3*a], dy=pos[3*b+1]-pos[3*a+1], dz=pos[3*b+2]-pos[3*a+2];
        float d=sqrtf(dx*dx+dy*dy+dz*dz);
        float inv=1.f/d;
        calc_sh(dx*inv,dy*inv,dz*inv,&shs[tid*16]);
        dd_[tid]=d;
        es_[tid]=x[b]*(0.18257418583505536f*0.4082482904638631f); // fold 1/sqrt30 * 1/sqrt6
        sl_[tid]=fs-2;
      }
    }
    __syncthreads();
    // A1: radial embedding, one (edge,i) per task
    for(int t=tid;t<cnt*20;t+=1024){
      int ee=t/20, i=t-ee*20;
      if(sl_[ee]>=0){
        const float inv_step=21.f/3.5f;
        const float pref=(float)(1.14136*7.3890560989306495);  // 1.14136*e^2
        float di=dd_[ee]*inv_step;
        float A=di-(float)i, B=(float)(i+2)-di;
        float ua=(A>0.f)?expf(-1.f/A):0.f;
        float ub=(B>0.f)?expf(-1.f/B):0.f;
        embs[ee*20+i]=pref*ua*ub;
      }
    }
    __syncthreads();
    // B: MLP layer 1, one (edge,j) per task: 20 independent LDS MACs
    for(int t=tid;t<cnt*30;t+=1024){
      int ee=t/30, j=t-ee*30;
      if(sl_[ee]>=0){
        float z=0.f;
        #pragma unroll
        for(int i=0;i<20;i++) z+=embs[ee*20+i]*W1s[i*30+j];
        z*=0.22360679774997896f;                  // 1/sqrt20
        hs[ee*30+j]=1.679177f*z/(1.f+expf(-z));   // NORM2MOM * silu
      }
    }
    __syncthreads();
    // C: MLP layer 2, one (edge,c) per task: 30 independent LDS MACs
    for(int t=tid;t<cnt*20;t+=1024){
      int ee=t/20, c=t-ee*20;
      if(sl_[ee]>=0){
        float v=0.f;
        #pragma unroll
        for(int j=0;j<30;j++) v+=hs[ee*30+j]*W2s[j*20+c];
        tws[ee*20+c]=v;
      }
    }
    __syncthreads();
    // D: mid accumulation, one (edge,out-of-80) per task
    for(int t=tid;t<cnt*80;t+=1024){
      int ee=t/80, oo=t-ee*80;
      int sl=sl_[ee];
      if(sl>=0){
        int l,u,mm;
        if(oo<5){ l=0; u=oo; mm=0; }
        else if(oo<20){ int r=oo-5;  l=1; u=r/3; mm=r-u*3; }
        else if(oo<45){ int r=oo-20; l=2; u=r/5; mm=r-u*5; }
        else          { int r=oo-45; l=3; u=r/7; mm=r-u*7; }
        float val=es_[ee]*tws[ee*20+l*5+u]*shs[ee*16+l*l+mm];
        atomicAdd(&nmid[sl*80+oo],val);
      }
    }
    __syncthreads();
  }

  // ---------------- phase 2: second tensor product over edges out of Co ----------------
  int ns=*numS; if(ns>CAP_S) ns=CAP_S;
  for(int base=0;base<ns;base+=EB){
    int cnt=min(EB,ns-base);
    if(tid<cnt){
      int e=S[base+tid];
      int a=efrom[e], b=eto[e];
      int fs=flagslot[b];
      if(fs<2){ sl_[tid]=-1; }
      else{
        float dx=pos[3*b]-pos[3*a], dy=pos[3*b+1]-pos[3*a+1], dz=pos[3*b+2]-pos[3*a+2];
        float d=sqrtf(dx*dx+dy*dy+dz*dz);
        float inv=1.f/d;
        calc_sh(dx*inv,dy*inv,dz*inv,&shs[tid*16]);
        sl_[tid]=fs-2;
      }
    }
    __syncthreads();
    // one (edge,path,u) per task
    for(int t=tid;t<cnt*35;t+=1024){
      int ee=t/35, r=t-ee*35, p=r/5, u=r-p*5;
      int sl=sl_[ee];
      if(sl>=0){
        int l1=(p+1)>>1;                         // 0,1,1,2,2,3,3
        int l2=(0x3636>>(2*p))&3;                // 2,1,3,0,2,1,3
        const unsigned long long wbpack=
          (25ULL<<9)|(70ULL<<18)|(175ULL<<27)|(200ULL<<36)|(325ULL<<45)|(430ULL<<54);
        int wb=(int)((wbpack>>(9*p))&511ULL);    // 0,25,70,175,200,325,430
        int n1=2*l1+1, n2=2*l2+1;
        float tu=tp2s[p*5+u];
        float o0=0.f,o1=0.f,o2=0.f,o3=0.f,o4=0.f;
        const float* mrow=&nmid[sl*80+5*l1*l1+u*n1];
        const float* shrow=&shs[ee*16+l2*l2];
        const float* Wp=&w3s[wb];
        for(int i=0;i<n1;i++){
          float mi=mrow[i]*tu;
          for(int j=0;j<n2;j++){
            float c=mi*shrow[j];
            const float* Wk=Wp+(i*n2+j)*5;
            o0+=Wk[0]*c; o1+=Wk[1]*c; o2+=Wk[2]*c; o3+=Wk[3]*c; o4+=Wk[4]*c;
          }
        }
        atomicAdd(&acc[0],o0); atomicAdd(&acc[1],o1); atomicAdd(&acc[2],o2);
        atomicAdd(&acc[3],o3); atomicAdd(&acc[4],o4);
      }
    }
    __syncthreads();
  }

  const float scale=0.37796447300922725f*0.4082482904638631f;  // ALPHA2 * 1/sqrt(6)
  if(tid<5) out5[tid]=acc[tid]*scale;
}

// ====================== launch ======================
extern "C" void kernel_launch(void* const* d_in, const int* in_sizes, int n_in,
                              void* d_out, int out_size, void* d_ws, size_t ws_size,
                              hipStream_t stream){
  const float* x    =(const float*)d_in[0];
  const float* pos  =(const float*)d_in[1];
  const int*   efrom=(const int*)  d_in[2];
  const int*   eto  =(const int*)  d_in[3];
  const float* W1   =(const float*)d_in[4];
  const float* W2   =(const float*)d_in[5];
  const float* tp2  =(const float*)d_in[6];
  int N=in_sizes[0], E=in_sizes[2];

  char* ws=(char*)d_ws;
  size_t o=0;
  int* counts=(int*)(ws+o);                 o+=(size_t)N*4;
  int* flagslot=(int*)(ws+o);               o+=(size_t)N*4;
  o=(o+15)&~(size_t)15;
  unsigned long long* packed=(unsigned long long*)(ws+o); o+=8;
  int* numS=(int*)(ws+o);                   o+=4;
  int* numT=(int*)(ws+o);                   o+=4;
  int* numM=(int*)(ws+o);                   o+=4;
  size_t o_clear=o;                         // everything above must start zeroed
  o=(o+15)&~(size_t)15;
  int* S=(int*)(ws+o);                      o+=(size_t)CAP_S*4;
  int* M=(int*)(ws+o);                      o+=(size_t)CAP_M*4;

  hipMemsetAsync(d_ws,0,o_clear,stream);  // ws is re-poisoned 0xAA before every call

  const int tb=256;
  int nQ=(E+3)/4;                       // 4 edges per thread in the E-scans
  int gQ=(nQ+tb-1)/tb, gN=(N+tb-1)/tb;
  k_bincount<<<gQ,tb,0,stream>>>(eto,E,counts);
  k_argmax  <<<gN,tb,0,stream>>>(counts,N,packed);
  k_collect <<<gQ,tb,0,stream>>>(efrom,eto,E,packed,S,numS,numT,flagslot);
  k_scanmid <<<gQ,tb,0,stream>>>(efrom,E,flagslot,M,numM);
  k_tail    <<<1,1024,0,stream>>>(x,pos,efrom,eto,W1,W2,tp2,flagslot,S,numS,M,numM,g_w3j,(float*)d_out);
}